// Round 1
// 473.344 us; speedup vs baseline: 1.1768x; 1.1768x over previous
//
#include <hip/hip_runtime.h>

// MultiPrecisionLinear: out[m,o] = sum_i x[m,i] * W[bits[path(m)],o,i] + bias[o]
// M = 262144 (8 paths x 32768 rows), K = 256, N = 256, fp32 in/out.
// Round 3: LDS-staged x-tile (bf16, XOR-swizzled), converted ONCE per block
// (was 4x redundant per wave); single bulk load burst per block (16 float4 /
// thread) instead of 8 dependent per-iter bursts; swapped MFMA operands
// (A=W, B=x) so D holds 4 consecutive output cols per lane -> float4 stores
// (16 per wave vs 64 scalar). B-frags (W) from bf16 bank pre-converted into
// d_ws, L1/L2-resident.

typedef float  floatx4  __attribute__((ext_vector_type(4)));
typedef short  shortx8  __attribute__((ext_vector_type(8)));
typedef unsigned short ushortx4 __attribute__((ext_vector_type(4)));

constexpr int DIN  = 256;
constexpr int DOUT = 256;
constexpr int ROWS_PER_PATH = 8 * 4096;   // bpp * S
constexpr int BM   = 64;                  // rows per block (4 waves x full N=256)
constexpr int WBANK_ELEMS = 7 * DOUT * DIN;

__device__ __forceinline__ unsigned short f2bf(float f) {
  // round-to-nearest-even fp32 -> bf16
  union { float f; unsigned u; } c; c.f = f;
  unsigned r = c.u + 0x7fffu + ((c.u >> 16) & 1u);
  return (unsigned short)(r >> 16);
}

__device__ __forceinline__ shortx8 cvt8(floatx4 v0, floatx4 v1) {
  shortx8 h;
  h[0] = (short)f2bf(v0.x); h[1] = (short)f2bf(v0.y);
  h[2] = (short)f2bf(v0.z); h[3] = (short)f2bf(v0.w);
  h[4] = (short)f2bf(v1.x); h[5] = (short)f2bf(v1.y);
  h[6] = (short)f2bf(v1.z); h[7] = (short)f2bf(v1.w);
  return h;
}

// one-time fp32 -> bf16 conversion of the 7-entry weight bank into d_ws
__global__ void convert_w_kernel(const float* __restrict__ w,
                                 unsigned short* __restrict__ o, int n4) {
  int i = blockIdx.x * 256 + threadIdx.x;
  if (i < n4) {
    floatx4 v = ((const floatx4*)w)[i];
    ushortx4 h;
    h.x = f2bf(v.x); h.y = f2bf(v.y); h.z = f2bf(v.z); h.w = f2bf(v.w);
    ((ushortx4*)o)[i] = h;
  }
}

template <bool WBF>
__global__ __launch_bounds__(256, 4)
void mp_linear_kernel(const float* __restrict__ x,
                      const void*  __restrict__ wsel,
                      const float* __restrict__ bias,
                      const int*   __restrict__ bits,
                      float* __restrict__ out) {
  // 64 rows x 256 k of bf16 x, rows XOR-swizzled (byte ^= (row&7)<<4) so
  // ds_read_b128 frag reads are conflict-free (2-way residual = free, m136).
  __shared__ short xs[BM * DIN];          // 32 KiB

  const int tid  = threadIdx.x;
  const int row0 = blockIdx.x * BM;
  const int path = row0 / ROWS_PER_PATH;
  const int widx = bits[path];

  const int lane = tid & 63;
  const int wave = tid >> 6;
  const int n0   = wave * 64;       // wave's N offset (4 waves cover N=256)
  const int quad = lane >> 4;
  const int l16  = lane & 15;

  // ---- stage x tile: one burst of 16 float4 loads / thread, cvt once ----
  {
    const float* xt = x + (size_t)row0 * DIN;
    floatx4 v[16];
#pragma unroll
    for (int c = 0; c < 8; ++c) {
      const float* p = xt + (size_t)(tid + c * 256) * 8;
      v[2 * c]     = *(const floatx4*)p;
      v[2 * c + 1] = *(const floatx4*)(p + 4);
    }
#pragma unroll
    for (int c = 0; c < 8; ++c) {
      const int g   = tid + c * 256;        // float8 chunk index
      const int row = g >> 5;               // 32 chunks per row
      const int col = (g & 31) * 8;         // in shorts
      int byte = (row * DIN + col) * 2;
      byte ^= (row & 7) << 4;               // swizzle applied to final addr
      *(shortx8*)((char*)xs + byte) = cvt8(v[2 * c], v[2 * c + 1]);
    }
  }
  __syncthreads();

  // A-operand = W: lane holds o = n0 + nf*16 + l16, k = quad*8 + j
  const unsigned short* __restrict__ wbf =
      (const unsigned short*)wsel + (size_t)widx * (DOUT * DIN)
      + (size_t)(n0 + l16) * DIN + quad * 8;
  const float* __restrict__ wf32 =
      (const float*)wsel + (size_t)widx * (DOUT * DIN)
      + (size_t)(n0 + l16) * DIN + quad * 8;

  floatx4 acc[4][4];
#pragma unroll
  for (int i = 0; i < 4; ++i)
#pragma unroll
    for (int j = 0; j < 4; ++j)
      acc[i][j] = (floatx4)0.f;

#pragma unroll 2
  for (int k0 = 0; k0 < DIN; k0 += 32) {
    shortx8 a[4], xf[4];
#pragma unroll
    for (int nf = 0; nf < 4; ++nf) {
      if (WBF) {
        a[nf] = *(const shortx8*)(wbf + (size_t)(nf * 16) * DIN + k0);
      } else {
        const float* p = wf32 + (size_t)(nf * 16) * DIN + k0;
        a[nf] = cvt8(*(const floatx4*)p, *(const floatx4*)(p + 4));
      }
    }
#pragma unroll
    for (int mf = 0; mf < 4; ++mf) {
      const int row = mf * 16 + l16;
      int byte = (row * DIN + k0 + quad * 8) * 2;
      byte ^= (row & 7) << 4;
      xf[mf] = *(const shortx8*)((const char*)xs + byte);
    }
#pragma unroll
    for (int mf = 0; mf < 4; ++mf)
#pragma unroll
      for (int nf = 0; nf < 4; ++nf)
        // swapped operands: A=W, B=x -> D[row=o_local, col=m_local]
        acc[mf][nf] = __builtin_amdgcn_mfma_f32_16x16x32_bf16(
            a[nf], xf[mf], acc[mf][nf], 0, 0, 0);
  }

  // epilogue: D layout col = lane&15 (m), row = quad*4 + r (o) -> each lane
  // holds 4 consecutive output cols of one row: float4 stores.
  floatx4 bv[4];
#pragma unroll
  for (int nf = 0; nf < 4; ++nf)
    bv[nf] = *(const floatx4*)(bias + n0 + nf * 16 + quad * 4);

#pragma unroll
  for (int mf = 0; mf < 4; ++mf) {
    float* orow = out + (size_t)(row0 + mf * 16 + l16) * DOUT + n0 + quad * 4;
#pragma unroll
    for (int nf = 0; nf < 4; ++nf) {
      floatx4 o4 = acc[mf][nf] + bv[nf];
      *(floatx4*)(orow + nf * 16) = o4;
    }
  }
}

extern "C" void kernel_launch(void* const* d_in, const int* in_sizes, int n_in,
                              void* d_out, int out_size, void* d_ws, size_t ws_size,
                              hipStream_t stream) {
  const float* x     = (const float*)d_in[0];
  const float* wbank = (const float*)d_in[1];
  const float* bias  = (const float*)d_in[2];
  const int*   bits  = (const int*)d_in[3];
  float*       out   = (float*)d_out;

  const int total_rows = in_sizes[0] / DIN;   // 262144
  const int grid = total_rows / BM;           // 4096

  const size_t wbf_bytes = (size_t)WBANK_ELEMS * sizeof(unsigned short);  // 917504
  if (ws_size >= wbf_bytes) {
    unsigned short* wbf = (unsigned short*)d_ws;
    const int n4 = WBANK_ELEMS / 4;           // 114688
    convert_w_kernel<<<(n4 + 255) / 256, 256, 0, stream>>>(wbank, wbf, n4);
    mp_linear_kernel<true><<<grid, 256, 0, stream>>>(x, wbf, bias, bits, out);
  } else {
    mp_linear_kernel<false><<<grid, 256, 0, stream>>>(x, wbank, bias, bits, out);
  }
}